// Round 2
// baseline (597.729 us; speedup 1.0000x reference)
//
#include <hip/hip_runtime.h>
#include <math.h>

#define KS  15
#define RAD 7
#define L   160
#define VOL (L*L*L)
#define WT  32
#define HT  16

struct Taps {
    float g[KS];   // normalized 1D gaussian
    float h[KS];   // (x^2 - s^2)/s^4 * g
    float m;       // kernel mean (subtracted constant)
    float scale;   // 1 / (N * VOL)
};

// ---------------- Pass 1: along W (contiguous). diff -> A,B,C ----------------
// Layout in/out: [d][h][w]
__global__ __launch_bounds__(320) void k_wpass(const float* __restrict__ pred,
                                               const float* __restrict__ tgt,
                                               float* __restrict__ A,
                                               float* __restrict__ B,
                                               float* __restrict__ C,
                                               Taps tp) {
    __shared__ float s[2][L + 2 * RAD];
    const int w  = threadIdx.x;          // 0..159
    const int ty = threadIdx.y;          // 0..1
    const int h  = blockIdx.x * 2 + ty;
    const int d  = blockIdx.y;
    const int base = (d * L + h) * L;

    s[ty][RAD + w] = pred[base + w] - tgt[base + w];
    if (w < RAD) { s[ty][w] = 0.f; s[ty][L + RAD + w] = 0.f; }
    __syncthreads();

    float a = 0.f, b = 0.f, c = 0.f;
#pragma unroll
    for (int t = 0; t < KS; ++t) {
        float v = s[ty][w + t];
        a += tp.g[t] * v;
        b += tp.h[t] * v;
        c += v;
    }
    A[base + w] = a;
    B[base + w] = b;
    C[base + w] = c;
}

// ---------------- Pass 2: along H. A,B,C -> P,Q,R ----------------
// Reads [d][h][w]; writes TRANSPOSED [h][d][w] so the D-pass reads stride-L rows.
__global__ __launch_bounds__(512) void k_hpass(const float* __restrict__ A,
                                               const float* __restrict__ B,
                                               const float* __restrict__ C,
                                               float* __restrict__ P,
                                               float* __restrict__ Q,
                                               float* __restrict__ R,
                                               Taps tp) {
    __shared__ float sA[HT + 2 * RAD][WT];
    __shared__ float sB[HT + 2 * RAD][WT];
    __shared__ float sC[HT + 2 * RAD][WT];
    const int tx = threadIdx.x, ty = threadIdx.y;
    const int w  = blockIdx.x * WT + tx;
    const int h0 = blockIdx.y * HT;
    const int d  = blockIdx.z;

    for (int r = ty; r < HT + 2 * RAD; r += HT) {
        int hs = h0 - RAD + r;
        bool ok = (hs >= 0) && (hs < L);
        int idx = (d * L + hs) * L + w;
        sA[r][tx] = ok ? A[idx] : 0.f;
        sB[r][tx] = ok ? B[idx] : 0.f;
        sC[r][tx] = ok ? C[idx] : 0.f;
    }
    __syncthreads();

    float p = 0.f, q = 0.f, rr = 0.f;
#pragma unroll
    for (int t = 0; t < KS; ++t) {
        float va = sA[ty + t][tx];
        float vb = sB[ty + t][tx];
        p  += tp.g[t] * va;
        q  += tp.h[t] * va + tp.g[t] * vb;
        rr += sC[ty + t][tx];
    }
    // transposed write: element (d, h0+ty, w) -> [(h0+ty)*L + d]*L + w
    const int idx = ((h0 + ty) * L + d) * L + w;
    P[idx] = p;
    Q[idx] = q;
    R[idx] = rr;
}

// ---------------- Pass 3: along D + |.| + reduction ----------------
// Reads TRANSPOSED [h][d][w]: halo rows are stride-L (640 B), DRAM-friendly.
__global__ __launch_bounds__(512) void k_dpass(const float* __restrict__ P,
                                               const float* __restrict__ Q,
                                               const float* __restrict__ R,
                                               float* __restrict__ out,
                                               Taps tp) {
    __shared__ float sP[HT + 2 * RAD][WT];
    __shared__ float sQ[HT + 2 * RAD][WT];
    __shared__ float sR[HT + 2 * RAD][WT];
    const int tx = threadIdx.x, ty = threadIdx.y;
    const int w  = blockIdx.x * WT + tx;
    const int d0 = blockIdx.y * HT;
    const int h  = blockIdx.z;

    for (int r = ty; r < HT + 2 * RAD; r += HT) {
        int ds = d0 - RAD + r;
        bool ok = (ds >= 0) && (ds < L);
        int idx = (h * L + ds) * L + w;   // transposed layout
        sP[r][tx] = ok ? P[idx] : 0.f;
        sQ[r][tx] = ok ? Q[idx] : 0.f;
        sR[r][tx] = ok ? R[idx] : 0.f;
    }
    __syncthreads();

    float f = 0.f, box = 0.f;
#pragma unroll
    for (int t = 0; t < KS; ++t) {
        f   += tp.h[t] * sP[ty + t][tx] + tp.g[t] * sQ[ty + t][tx];
        box += sR[ty + t][tx];
    }
    f -= tp.m * box;
    float val = fabsf(f) * tp.scale;

    // 64-lane wave reduce, then cross-wave via LDS, one atomic per block
#pragma unroll
    for (int off = 32; off > 0; off >>= 1) val += __shfl_down(val, off);

    __shared__ float wsum[8];
    const int tid  = ty * WT + tx;
    const int lane = tid & 63;
    const int wid  = tid >> 6;
    if (lane == 0) wsum[wid] = val;
    __syncthreads();
    if (wid == 0) {
        float v = (lane < 8) ? wsum[lane] : 0.f;
#pragma unroll
        for (int off = 4; off > 0; off >>= 1) v += __shfl_down(v, off);
        if (lane == 0) atomicAdd(out, v);
    }
}

extern "C" void kernel_launch(void* const* d_in, const int* in_sizes, int n_in,
                              void* d_out, int out_size, void* d_ws, size_t ws_size,
                              hipStream_t stream) {
    const float* pred = (const float*)d_in[0];
    const float* tgt  = (const float*)d_in[1];
    float* out = (float*)d_out;
    float* ws  = (float*)d_ws;

    // Build 1D taps on host (double precision, cast to float)
    Taps tp;
    const double sigma = 1.5;
    double g1[KS], S = 0.0;
    for (int i = 0; i < KS; ++i) {
        double x = (double)(i - RAD);
        g1[i] = exp(-x * x / (2.0 * sigma * sigma));
        S += g1[i];
    }
    double sumH = 0.0;
    for (int i = 0; i < KS; ++i) {
        double x = (double)(i - RAD);
        double G = g1[i] / S;
        double H = (x * x - sigma * sigma) / (sigma * sigma * sigma * sigma) * G;
        tp.g[i] = (float)G;
        tp.h[i] = (float)H;
        sumH += H;
    }
    tp.m     = (float)(3.0 * sumH / (double)(KS * KS * KS));
    tp.scale = 1.0f / (4.0f * (float)VOL);

    float* A = ws + (size_t)0 * VOL;
    float* B = ws + (size_t)1 * VOL;
    float* C = ws + (size_t)2 * VOL;
    float* P = ws + (size_t)3 * VOL;
    float* Q = ws + (size_t)4 * VOL;
    float* R = ws + (size_t)5 * VOL;

    hipMemsetAsync(d_out, 0, sizeof(float), stream);

    for (int n = 0; n < 4; ++n) {
        const float* pn = pred + (size_t)n * VOL;
        const float* tn = tgt  + (size_t)n * VOL;
        k_wpass<<<dim3(L / 2, L), dim3(L, 2), 0, stream>>>(pn, tn, A, B, C, tp);
        k_hpass<<<dim3(L / WT, L / HT, L), dim3(WT, HT), 0, stream>>>(A, B, C, P, Q, R, tp);
        k_dpass<<<dim3(L / WT, L / HT, L), dim3(WT, HT), 0, stream>>>(P, Q, R, out, tp);
    }
}

// Round 3
// 289.036 us; speedup vs baseline: 2.0680x; 2.0680x over previous
//
#include <hip/hip_runtime.h>
#include <math.h>

#define KS  15
#define RAD 7
#define L   160
#define VOL (L*L*L)
#define WT  32
#define HT  16
#define NBLK (5 * 10 * 160)   // dpass grid: (L/WT) * (L/HT) * L

struct Taps {
    float g[KS];   // normalized 1D gaussian
    float h[KS];   // (x^2 - s^2)/s^4 * g
    float m;       // kernel mean (subtracted constant)
    float scale;   // 1 / (N * VOL)
};

// ---------------- Pass 1: along W (contiguous). diff -> A,B,C ----------------
// Layout in/out: [d][h][w]
__global__ __launch_bounds__(320) void k_wpass(const float* __restrict__ pred,
                                               const float* __restrict__ tgt,
                                               float* __restrict__ A,
                                               float* __restrict__ B,
                                               float* __restrict__ C,
                                               Taps tp) {
    __shared__ float s[2][L + 2 * RAD];
    const int w  = threadIdx.x;          // 0..159
    const int ty = threadIdx.y;          // 0..1
    const int h  = blockIdx.x * 2 + ty;
    const int d  = blockIdx.y;
    const int base = (d * L + h) * L;

    s[ty][RAD + w] = pred[base + w] - tgt[base + w];
    if (w < RAD) { s[ty][w] = 0.f; s[ty][L + RAD + w] = 0.f; }
    __syncthreads();

    float a = 0.f, b = 0.f, c = 0.f;
#pragma unroll
    for (int t = 0; t < KS; ++t) {
        float v = s[ty][w + t];
        a += tp.g[t] * v;
        b += tp.h[t] * v;
        c += v;
    }
    A[base + w] = a;
    B[base + w] = b;
    C[base + w] = c;
}

// ---------------- Pass 2: along H. A,B,C -> P,Q,R ----------------
// Reads [d][h][w]; writes TRANSPOSED [h][d][w] so the D-pass reads stride-L rows.
__global__ __launch_bounds__(512) void k_hpass(const float* __restrict__ A,
                                               const float* __restrict__ B,
                                               const float* __restrict__ C,
                                               float* __restrict__ P,
                                               float* __restrict__ Q,
                                               float* __restrict__ R,
                                               Taps tp) {
    __shared__ float sA[HT + 2 * RAD][WT];
    __shared__ float sB[HT + 2 * RAD][WT];
    __shared__ float sC[HT + 2 * RAD][WT];
    const int tx = threadIdx.x, ty = threadIdx.y;
    const int w  = blockIdx.x * WT + tx;
    const int h0 = blockIdx.y * HT;
    const int d  = blockIdx.z;

    for (int r = ty; r < HT + 2 * RAD; r += HT) {
        int hs = h0 - RAD + r;
        bool ok = (hs >= 0) && (hs < L);
        int idx = (d * L + hs) * L + w;
        sA[r][tx] = ok ? A[idx] : 0.f;
        sB[r][tx] = ok ? B[idx] : 0.f;
        sC[r][tx] = ok ? C[idx] : 0.f;
    }
    __syncthreads();

    float p = 0.f, q = 0.f, rr = 0.f;
#pragma unroll
    for (int t = 0; t < KS; ++t) {
        float va = sA[ty + t][tx];
        float vb = sB[ty + t][tx];
        p  += tp.g[t] * va;
        q  += tp.h[t] * va + tp.g[t] * vb;
        rr += sC[ty + t][tx];
    }
    // transposed write: element (d, h0+ty, w) -> [(h0+ty)*L + d]*L + w
    const int idx = ((h0 + ty) * L + d) * L + w;
    P[idx] = p;
    Q[idx] = q;
    R[idx] = rr;
}

// ---------------- Pass 3: along D + |.| -> per-block partial ----------------
// Reads TRANSPOSED [h][d][w]. NO global atomics: one partial store per block.
__global__ __launch_bounds__(512) void k_dpass(const float* __restrict__ P,
                                               const float* __restrict__ Q,
                                               const float* __restrict__ R,
                                               float* __restrict__ partial,
                                               Taps tp) {
    __shared__ float sP[HT + 2 * RAD][WT];
    __shared__ float sQ[HT + 2 * RAD][WT];
    __shared__ float sR[HT + 2 * RAD][WT];
    const int tx = threadIdx.x, ty = threadIdx.y;
    const int w  = blockIdx.x * WT + tx;
    const int d0 = blockIdx.y * HT;
    const int h  = blockIdx.z;

    for (int r = ty; r < HT + 2 * RAD; r += HT) {
        int ds = d0 - RAD + r;
        bool ok = (ds >= 0) && (ds < L);
        int idx = (h * L + ds) * L + w;   // transposed layout
        sP[r][tx] = ok ? P[idx] : 0.f;
        sQ[r][tx] = ok ? Q[idx] : 0.f;
        sR[r][tx] = ok ? R[idx] : 0.f;
    }
    __syncthreads();

    float f = 0.f, box = 0.f;
#pragma unroll
    for (int t = 0; t < KS; ++t) {
        f   += tp.h[t] * sP[ty + t][tx] + tp.g[t] * sQ[ty + t][tx];
        box += sR[ty + t][tx];
    }
    f -= tp.m * box;
    float val = fabsf(f) * tp.scale;

    // 64-lane wave reduce, then cross-wave via LDS, ONE STORE per block
#pragma unroll
    for (int off = 32; off > 0; off >>= 1) val += __shfl_down(val, off);

    __shared__ float wsum[8];
    const int tid  = ty * WT + tx;
    const int lane = tid & 63;
    const int wid  = tid >> 6;
    if (lane == 0) wsum[wid] = val;
    __syncthreads();
    if (wid == 0) {
        float v = (lane < 8) ? wsum[lane] : 0.f;
#pragma unroll
        for (int off = 4; off > 0; off >>= 1) v += __shfl_down(v, off);
        if (lane == 0) {
            const int bid = (blockIdx.z * gridDim.y + blockIdx.y) * gridDim.x + blockIdx.x;
            partial[bid] = v;
        }
    }
}

// ---------------- Final: sum NBLK partials, one atomic per launch ----------------
__global__ __launch_bounds__(1024) void k_reduce(const float* __restrict__ partial,
                                                 float* __restrict__ out) {
    float v = 0.f;
    for (int i = threadIdx.x; i < NBLK; i += 1024) v += partial[i];
#pragma unroll
    for (int off = 32; off > 0; off >>= 1) v += __shfl_down(v, off);

    __shared__ float wsum[16];
    const int lane = threadIdx.x & 63;
    const int wid  = threadIdx.x >> 6;
    if (lane == 0) wsum[wid] = v;
    __syncthreads();
    if (wid == 0) {
        float s = (lane < 16) ? wsum[lane] : 0.f;
#pragma unroll
        for (int off = 8; off > 0; off >>= 1) s += __shfl_down(s, off);
        if (lane == 0) atomicAdd(out, s);
    }
}

extern "C" void kernel_launch(void* const* d_in, const int* in_sizes, int n_in,
                              void* d_out, int out_size, void* d_ws, size_t ws_size,
                              hipStream_t stream) {
    const float* pred = (const float*)d_in[0];
    const float* tgt  = (const float*)d_in[1];
    float* out = (float*)d_out;
    float* ws  = (float*)d_ws;

    // Build 1D taps on host (double precision, cast to float)
    Taps tp;
    const double sigma = 1.5;
    double g1[KS], S = 0.0;
    for (int i = 0; i < KS; ++i) {
        double x = (double)(i - RAD);
        g1[i] = exp(-x * x / (2.0 * sigma * sigma));
        S += g1[i];
    }
    double sumH = 0.0;
    for (int i = 0; i < KS; ++i) {
        double x = (double)(i - RAD);
        double G = g1[i] / S;
        double H = (x * x - sigma * sigma) / (sigma * sigma * sigma * sigma) * G;
        tp.g[i] = (float)G;
        tp.h[i] = (float)H;
        sumH += H;
    }
    tp.m     = (float)(3.0 * sumH / (double)(KS * KS * KS));
    tp.scale = 1.0f / (4.0f * (float)VOL);

    float* A = ws + (size_t)0 * VOL;   // also reused as partials during dpass
    float* B = ws + (size_t)1 * VOL;
    float* C = ws + (size_t)2 * VOL;
    float* P = ws + (size_t)3 * VOL;
    float* Q = ws + (size_t)4 * VOL;
    float* R = ws + (size_t)5 * VOL;

    hipMemsetAsync(d_out, 0, sizeof(float), stream);

    for (int n = 0; n < 4; ++n) {
        const float* pn = pred + (size_t)n * VOL;
        const float* tn = tgt  + (size_t)n * VOL;
        k_wpass<<<dim3(L / 2, L), dim3(L, 2), 0, stream>>>(pn, tn, A, B, C, tp);
        k_hpass<<<dim3(L / WT, L / HT, L), dim3(WT, HT), 0, stream>>>(A, B, C, P, Q, R, tp);
        // A is dead here (next wpass rewrites it): use it for per-block partials
        k_dpass<<<dim3(L / WT, L / HT, L), dim3(WT, HT), 0, stream>>>(P, Q, R, A, tp);
        k_reduce<<<1, 1024, 0, stream>>>(A, out);
    }
}

// Round 4
// 237.297 us; speedup vs baseline: 2.5189x; 1.2180x over previous
//
#include <hip/hip_runtime.h>
#include <math.h>

#define KS   15
#define RAD  7
#define L    160
#define VOL  (L*L*L)
#define NB   4          // batch
#define HT   32         // k_wh h-tile
#define HALO (HT + 2*RAD)   // 46
#define LP   176        // sdiff row stride (pad, 16B-aligned)
#define LA   168        // sA/sB/sC row stride (16B-aligned, bank-uniform)
#define DT   40         // k_d d-chunk per thread
#define NBLK (5*10*16)  // k_d grid blocks = 800

struct Taps {
    float g[KS];
    float h[KS];
    float m;
    float scale;
};

// ============ Kernel 1: diff + W-conv + H-conv fused ============
// grid (5 h-tiles, 160 d, 4 n), block (160, 4).
// Writes P,Q,R in TRANSPOSED layout [n][h][d][w].
__global__ __launch_bounds__(640) void k_wh(const float* __restrict__ pred,
                                            const float* __restrict__ tgt,
                                            float* __restrict__ P,
                                            float* __restrict__ Q,
                                            float* __restrict__ R,
                                            Taps tp) {
    __shared__ float sd[HALO][LP];
    __shared__ float sA[HALO][LA];
    __shared__ float sB[HALO][LA];
    __shared__ float sC[HALO][LA];

    const int tx = threadIdx.x;            // 0..159 (w)
    const int ty = threadIdx.y;            // 0..3
    const int h0 = blockIdx.x * HT;
    const int d  = blockIdx.y;
    const int n  = blockIdx.z;
    const size_t nbase = (size_t)n * VOL;

    // ---- stage 1: load halo rows, diff, zero-pad w edges ----
    for (int r = ty; r < HALO; r += 4) {
        int hs = h0 - RAD + r;
        float v = 0.f;
        if (hs >= 0 && hs < L) {
            int idx = (d * L + hs) * L + tx;
            v = pred[nbase + idx] - tgt[nbase + idx];
        }
        sd[r][RAD + tx] = v;
        if (tx < RAD) { sd[r][tx] = 0.f; sd[r][L + RAD + tx] = 0.f; }
    }
    __syncthreads();

    // ---- stage 2: W-conv, 8 consecutive outputs per thread (sliding) ----
    {
        const int tid = ty * 160 + tx;
        const int j  = tid % 20;          // w-group
        const int w0 = 8 * j;
        for (int r = tid / 20; r < HALO; r += 32) {
            float v[24];
#pragma unroll
            for (int qq = 0; qq < 6; ++qq) {
                float4 t4 = *reinterpret_cast<const float4*>(&sd[r][w0 + 4*qq]);
                v[4*qq+0] = t4.x; v[4*qq+1] = t4.y; v[4*qq+2] = t4.z; v[4*qq+3] = t4.w;
            }
            float a[8], b[8], c[8];
#pragma unroll
            for (int k = 0; k < 8; ++k) {
                float aa = 0.f, bb = 0.f, cc = 0.f;
#pragma unroll
                for (int t = 0; t < KS; ++t) {
                    float x = v[k + t];
                    aa += tp.g[t] * x;
                    bb += tp.h[t] * x;
                    cc += x;
                }
                a[k] = aa; b[k] = bb; c[k] = cc;
            }
#pragma unroll
            for (int qq = 0; qq < 2; ++qq) {
                *reinterpret_cast<float4*>(&sA[r][w0 + 4*qq]) =
                    make_float4(a[4*qq], a[4*qq+1], a[4*qq+2], a[4*qq+3]);
                *reinterpret_cast<float4*>(&sB[r][w0 + 4*qq]) =
                    make_float4(b[4*qq], b[4*qq+1], b[4*qq+2], b[4*qq+3]);
                *reinterpret_cast<float4*>(&sC[r][w0 + 4*qq]) =
                    make_float4(c[4*qq], c[4*qq+1], c[4*qq+2], c[4*qq+3]);
            }
        }
    }
    __syncthreads();

    // ---- stage 3: H-conv, ty owns 8 consecutive h rows (sliding) ----
    {
        float p[8], q8[8], rr[8];
#pragma unroll
        for (int k = 0; k < 8; ++k) { p[k] = 0.f; q8[k] = 0.f; rr[k] = 0.f; }
#pragma unroll
        for (int jrow = 0; jrow < 8 + 2*RAD; ++jrow) {   // 22 rows
            float va = sA[8*ty + jrow][tx];
            float vb = sB[8*ty + jrow][tx];
            float vc = sC[8*ty + jrow][tx];
#pragma unroll
            for (int k = 0; k < 8; ++k) {
                int t = jrow - k;
                if (t >= 0 && t < KS) {
                    p[k]  += tp.g[t] * va;
                    q8[k] += tp.h[t] * va + tp.g[t] * vb;
                    rr[k] += vc;
                }
            }
        }
#pragma unroll
        for (int k = 0; k < 8; ++k) {
            int h = h0 + 8*ty + k;
            size_t o = nbase + ((size_t)h * L + d) * L + tx;   // transposed [h][d][w]
            P[o] = p[k]; Q[o] = q8[k]; R[o] = rr[k];
        }
    }
}

// ============ Kernel 2: D-conv streaming + |.| + block reduce ============
// grid (5 w-groups, 10 h-groups, 16 = n*4 + dchunk), block (32,16).
// Register ring, no LDS for data; P/Q/R reads are L3-resident.
__global__ __launch_bounds__(512) void k_d(const float* __restrict__ P,
                                           const float* __restrict__ Q,
                                           const float* __restrict__ R,
                                           float* __restrict__ partial,
                                           Taps tp) {
    const int tx = threadIdx.x;          // 0..31 (w)
    const int ty = threadIdx.y;          // 0..15 (h)
    const int w  = blockIdx.x * 32 + tx;
    const int h  = blockIdx.y * 16 + ty;
    const int gz = blockIdx.z;
    const int n  = gz >> 2;
    const int dc = gz & 3;
    const int d0 = dc * DT;

    const size_t base = (size_t)n * VOL + ((size_t)h * L) * L + w;  // + d*L
    const float* Pp = P + base;
    const float* Qp = Q + base;
    const float* Rp = R + base;

    float rp[KS], rq[KS], rc[KS];
    float box = 0.f;

    // prime ring with slices d0-7 .. d0+6
#pragma unroll
    for (int i = 0; i < KS - 1; ++i) {
        int s = d0 - RAD + i;            // <= 126, only s<0 possible OOB
        bool ok = (s >= 0);
        int off = s * L;
        float vp = ok ? Pp[off] : 0.f;
        float vq = ok ? Qp[off] : 0.f;
        float vc = ok ? Rp[off] : 0.f;
        rp[i] = vp; rq[i] = vq; rc[i] = vc;
        box += vc;
    }

    float acc = 0.f;
#pragma unroll
    for (int k = 0; k < DT; ++k) {
        int s = d0 + RAD + k;            // >= 7, only s>=L possible OOB
        bool ok = (s < L);
        int off = s * L;
        float vp = ok ? Pp[off] : 0.f;
        float vq = ok ? Qp[off] : 0.f;
        float vc = ok ? Rp[off] : 0.f;
        const int ri = (KS - 1 + k) % KS;
        rp[ri] = vp; rq[ri] = vq; rc[ri] = vc;
        box += vc;

        float f = 0.f;
#pragma unroll
        for (int t = 0; t < KS; ++t) {
            const int ii = (k + t) % KS;
            f += tp.h[t] * rp[ii] + tp.g[t] * rq[ii];
        }
        f -= tp.m * box;
        acc += fabsf(f);

        box -= rc[k % KS];               // drop slice d0+k-7
    }
    acc *= tp.scale;

    // block reduction, one plain store per block
#pragma unroll
    for (int off = 32; off > 0; off >>= 1) acc += __shfl_down(acc, off);

    __shared__ float wsum[8];
    const int tid  = ty * 32 + tx;
    const int lane = tid & 63;
    const int wid  = tid >> 6;
    if (lane == 0) wsum[wid] = acc;
    __syncthreads();
    if (wid == 0) {
        float v = (lane < 8) ? wsum[lane] : 0.f;
#pragma unroll
        for (int off = 4; off > 0; off >>= 1) v += __shfl_down(v, off);
        if (lane == 0) {
            const int bid = (gz * gridDim.y + blockIdx.y) * gridDim.x + blockIdx.x;
            partial[bid] = v;
        }
    }
}

// ============ Final: sum 800 partials, single block, plain store ============
__global__ __launch_bounds__(1024) void k_reduce(const float* __restrict__ partial,
                                                 float* __restrict__ out) {
    float v = 0.f;
    for (int i = threadIdx.x; i < NBLK; i += 1024) v += partial[i];
#pragma unroll
    for (int off = 32; off > 0; off >>= 1) v += __shfl_down(v, off);

    __shared__ float wsum[16];
    const int lane = threadIdx.x & 63;
    const int wid  = threadIdx.x >> 6;
    if (lane == 0) wsum[wid] = v;
    __syncthreads();
    if (wid == 0) {
        float s = (lane < 16) ? wsum[lane] : 0.f;
#pragma unroll
        for (int off = 8; off > 0; off >>= 1) s += __shfl_down(s, off);
        if (lane == 0) out[0] = s;       // single block: plain store, no atomic
    }
}

extern "C" void kernel_launch(void* const* d_in, const int* in_sizes, int n_in,
                              void* d_out, int out_size, void* d_ws, size_t ws_size,
                              hipStream_t stream) {
    const float* pred = (const float*)d_in[0];
    const float* tgt  = (const float*)d_in[1];
    float* out = (float*)d_out;
    float* ws  = (float*)d_ws;

    Taps tp;
    const double sigma = 1.5;
    double g1[KS], S = 0.0;
    for (int i = 0; i < KS; ++i) {
        double x = (double)(i - RAD);
        g1[i] = exp(-x * x / (2.0 * sigma * sigma));
        S += g1[i];
    }
    double sumH = 0.0;
    for (int i = 0; i < KS; ++i) {
        double x = (double)(i - RAD);
        double G = g1[i] / S;
        double H = (x * x - sigma * sigma) / (sigma * sigma * sigma * sigma) * G;
        tp.g[i] = (float)G;
        tp.h[i] = (float)H;
        sumH += H;
    }
    tp.m     = (float)(3.0 * sumH / (double)(KS * KS * KS));
    tp.scale = 1.0f / ((float)NB * (float)VOL);

    // ws: P[4*VOL] | Q[4*VOL] | R[4*VOL] | partial[800]  = ~196.6 MB + 3.2 KB
    float* P       = ws + (size_t)0 * NB * VOL;
    float* Q       = ws + (size_t)1 * NB * VOL;
    float* R       = ws + (size_t)2 * NB * VOL;
    float* partial = ws + (size_t)3 * NB * VOL;

    k_wh<<<dim3(L / HT, L, NB), dim3(160, 4), 0, stream>>>(pred, tgt, P, Q, R, tp);
    k_d<<<dim3(5, 10, NB * 4), dim3(32, 16), 0, stream>>>(P, Q, R, partial, tp);
    k_reduce<<<1, 1024, 0, stream>>>(partial, out);
}

// Round 5
// 201.009 us; speedup vs baseline: 2.9736x; 1.1805x over previous
//
#include <hip/hip_runtime.h>
#include <math.h>

#define KS   15
#define RAD  7
#define L    160
#define VOL  (L*L*L)
#define NB   4
#define HT   16             // output h-rows per k_wh block
#define HALO (HT + 2*RAD)   // 30
#define LA   164            // LDS row stride (16B-aligned: 164*4=656)
#define DT   40             // k_d d-chunk per thread
#define NBLK (5*10*16)      // k_d grid blocks = 800

struct Taps {
    float g[KS];   // normalized 1D gaussian (symmetric)
    float h[KS];   // (x^2 - s^2)/s^4 * g (symmetric)
    float m;       // kernel mean (subtracted constant)
    float scale;   // 1 / (N * VOL)
};

// zero-padded float4 load from a row of length L
__device__ __forceinline__ float4 ld4z(const float* __restrict__ p, int w) {
    if (w >= 0 && w + 3 < L) return *reinterpret_cast<const float4*>(p + w);
    float4 r;
    r.x = (w     >= 0 && w     < L) ? p[w]     : 0.f;
    r.y = (w + 1 >= 0 && w + 1 < L) ? p[w + 1] : 0.f;
    r.z = (w + 2 >= 0 && w + 2 < L) ? p[w + 2] : 0.f;
    r.w = (w + 3 >= 0 && w + 3 < L) ? p[w + 3] : 0.f;
    return r;
}

// ============ Kernel 1: diff + W-conv + H-conv fused (LDS = A,B,C only) ======
// grid (10 h-tiles, 160 d, 4 n), block (160,4)=640.
// Writes P,Q,R in TRANSPOSED layout [n][h][d][w].
__global__ __launch_bounds__(640) void k_wh(const float* __restrict__ pred,
                                            const float* __restrict__ tgt,
                                            float* __restrict__ P,
                                            float* __restrict__ Q,
                                            float* __restrict__ R,
                                            Taps tp) {
    __shared__ float sA[HALO][LA];
    __shared__ float sB[HALO][LA];
    __shared__ float sC[HALO][LA];

    const int tx = threadIdx.x, ty = threadIdx.y;
    const int tid = ty * 160 + tx;
    const int h0 = blockIdx.x * HT;
    const int d  = blockIdx.y;
    const int n  = blockIdx.z;
    const size_t nbase = (size_t)n * VOL;
    const float* prow = pred + nbase + (size_t)d * L * L;
    const float* trow = tgt  + nbase + (size_t)d * L * L;

    // ---- Stage A: load+diff+W-conv, 4 outputs per task, no sd buffer ----
    // tasks = HALO rows x 40 w-groups; lanes -> consecutive float4s (coalesced,
    // LDS writes 2-way max = free)
    for (int t = tid; t < HALO * 40; t += 640) {
        const int r = t / 40;            // 0..29
        const int j = t % 40;            // w-group
        const int h = h0 - RAD + r;
        float a[4], b[4], c[4];
        if (h >= 0 && h < L) {
            const float* pr = prow + h * L;
            const float* tr = trow + h * L;
            const int w0 = 4 * j - 8;    // window [4j-7, 4j+10] lives in [w0, w0+19]
            float dv[20];
#pragma unroll
            for (int q5 = 0; q5 < 5; ++q5) {
                float4 pv = ld4z(pr, w0 + 4 * q5);
                float4 tv = ld4z(tr, w0 + 4 * q5);
                dv[4*q5+0] = pv.x - tv.x;
                dv[4*q5+1] = pv.y - tv.y;
                dv[4*q5+2] = pv.z - tv.z;
                dv[4*q5+3] = pv.w - tv.w;
            }
#pragma unroll
            for (int k = 0; k < 4; ++k) {
                float mid = dv[k + 8];
                float aa = tp.g[7] * mid;
                float bb = tp.h[7] * mid;
                float cc = mid;
#pragma unroll
                for (int u = 0; u < 7; ++u) {     // symmetric taps: g[u]==g[14-u]
                    float s = dv[k + 1 + u] + dv[k + 15 - u];
                    aa += tp.g[u] * s;
                    bb += tp.h[u] * s;
                    cc += s;
                }
                a[k] = aa; b[k] = bb; c[k] = cc;
            }
        } else {
#pragma unroll
            for (int k = 0; k < 4; ++k) { a[k] = 0.f; b[k] = 0.f; c[k] = 0.f; }
        }
        *reinterpret_cast<float4*>(&sA[r][4*j]) = make_float4(a[0], a[1], a[2], a[3]);
        *reinterpret_cast<float4*>(&sB[r][4*j]) = make_float4(b[0], b[1], b[2], b[3]);
        *reinterpret_cast<float4*>(&sC[r][4*j]) = make_float4(c[0], c[1], c[2], c[3]);
    }
    __syncthreads();

    // ---- Stage B: H-conv; thread owns 4 consecutive h-rows at col tx ----
    // (row-wise b32 reads, lanes spread over w -> conflict-free; 18 reads/4 outs)
    {
        float A18[18], B18[18], C18[18];
#pragma unroll
        for (int i = 0; i < 18; ++i) {
            A18[i] = sA[4*ty + i][tx];
            B18[i] = sB[4*ty + i][tx];
            C18[i] = sC[4*ty + i][tx];
        }
        float rr = 0.f;
#pragma unroll
        for (int t = 0; t < KS; ++t) rr += C18[t];
#pragma unroll
        for (int k = 0; k < 4; ++k) {
            float p = 0.f, q = 0.f;
#pragma unroll
            for (int t = 0; t < KS; ++t) {
                p += tp.g[t] * A18[k + t];
                q += tp.h[t] * A18[k + t] + tp.g[t] * B18[k + t];
            }
            const int h = h0 + 4*ty + k;
            const size_t o = nbase + ((size_t)h * L + d) * L + tx;  // [n][h][d][w]
            P[o] = p; Q[o] = q; R[o] = rr;
            if (k < 3) rr += C18[k + 15] - C18[k];   // incremental box along h
        }
    }
}

// ============ Kernel 2: D-conv streaming + |.| + block reduce (unchanged) ====
__global__ __launch_bounds__(512) void k_d(const float* __restrict__ P,
                                           const float* __restrict__ Q,
                                           const float* __restrict__ R,
                                           float* __restrict__ partial,
                                           Taps tp) {
    const int tx = threadIdx.x;          // 0..31 (w)
    const int ty = threadIdx.y;          // 0..15 (h)
    const int w  = blockIdx.x * 32 + tx;
    const int h  = blockIdx.y * 16 + ty;
    const int gz = blockIdx.z;
    const int n  = gz >> 2;
    const int dc = gz & 3;
    const int d0 = dc * DT;

    const size_t base = (size_t)n * VOL + ((size_t)h * L) * L + w;  // + d*L
    const float* Pp = P + base;
    const float* Qp = Q + base;
    const float* Rp = R + base;

    float rp[KS], rq[KS], rc[KS];
    float box = 0.f;

#pragma unroll
    for (int i = 0; i < KS - 1; ++i) {
        int s = d0 - RAD + i;
        bool ok = (s >= 0);
        int off = s * L;
        float vp = ok ? Pp[off] : 0.f;
        float vq = ok ? Qp[off] : 0.f;
        float vc = ok ? Rp[off] : 0.f;
        rp[i] = vp; rq[i] = vq; rc[i] = vc;
        box += vc;
    }

    float acc = 0.f;
#pragma unroll
    for (int k = 0; k < DT; ++k) {
        int s = d0 + RAD + k;
        bool ok = (s < L);
        int off = s * L;
        float vp = ok ? Pp[off] : 0.f;
        float vq = ok ? Qp[off] : 0.f;
        float vc = ok ? Rp[off] : 0.f;
        const int ri = (KS - 1 + k) % KS;
        rp[ri] = vp; rq[ri] = vq; rc[ri] = vc;
        box += vc;

        float f = 0.f;
#pragma unroll
        for (int t = 0; t < KS; ++t) {
            const int ii = (k + t) % KS;
            f += tp.h[t] * rp[ii] + tp.g[t] * rq[ii];
        }
        f -= tp.m * box;
        acc += fabsf(f);

        box -= rc[k % KS];
    }
    acc *= tp.scale;

#pragma unroll
    for (int off = 32; off > 0; off >>= 1) acc += __shfl_down(acc, off);

    __shared__ float wsum[8];
    const int tid  = ty * 32 + tx;
    const int lane = tid & 63;
    const int wid  = tid >> 6;
    if (lane == 0) wsum[wid] = acc;
    __syncthreads();
    if (wid == 0) {
        float v = (lane < 8) ? wsum[lane] : 0.f;
#pragma unroll
        for (int off = 4; off > 0; off >>= 1) v += __shfl_down(v, off);
        if (lane == 0) {
            const int bid = (gz * gridDim.y + blockIdx.y) * gridDim.x + blockIdx.x;
            partial[bid] = v;
        }
    }
}

// ============ Final: sum 800 partials, single block, plain store ============
__global__ __launch_bounds__(1024) void k_reduce(const float* __restrict__ partial,
                                                 float* __restrict__ out) {
    float v = 0.f;
    for (int i = threadIdx.x; i < NBLK; i += 1024) v += partial[i];
#pragma unroll
    for (int off = 32; off > 0; off >>= 1) v += __shfl_down(v, off);

    __shared__ float wsum[16];
    const int lane = threadIdx.x & 63;
    const int wid  = threadIdx.x >> 6;
    if (lane == 0) wsum[wid] = v;
    __syncthreads();
    if (wid == 0) {
        float s = (lane < 16) ? wsum[lane] : 0.f;
#pragma unroll
        for (int off = 8; off > 0; off >>= 1) s += __shfl_down(s, off);
        if (lane == 0) out[0] = s;
    }
}

extern "C" void kernel_launch(void* const* d_in, const int* in_sizes, int n_in,
                              void* d_out, int out_size, void* d_ws, size_t ws_size,
                              hipStream_t stream) {
    const float* pred = (const float*)d_in[0];
    const float* tgt  = (const float*)d_in[1];
    float* out = (float*)d_out;
    float* ws  = (float*)d_ws;

    Taps tp;
    const double sigma = 1.5;
    double g1[KS], S = 0.0;
    for (int i = 0; i < KS; ++i) {
        double x = (double)(i - RAD);
        g1[i] = exp(-x * x / (2.0 * sigma * sigma));
        S += g1[i];
    }
    double sumH = 0.0;
    for (int i = 0; i < KS; ++i) {
        double x = (double)(i - RAD);
        double G = g1[i] / S;
        double H = (x * x - sigma * sigma) / (sigma * sigma * sigma * sigma) * G;
        tp.g[i] = (float)G;
        tp.h[i] = (float)H;
        sumH += H;
    }
    tp.m     = (float)(3.0 * sumH / (double)(KS * KS * KS));
    tp.scale = 1.0f / ((float)NB * (float)VOL);

    // ws: P[4*VOL] | Q[4*VOL] | R[4*VOL] | partial[800]
    float* Pb      = ws + (size_t)0 * NB * VOL;
    float* Qb      = ws + (size_t)1 * NB * VOL;
    float* Rb      = ws + (size_t)2 * NB * VOL;
    float* partial = ws + (size_t)3 * NB * VOL;

    k_wh<<<dim3(L / HT, L, NB), dim3(160, 4), 0, stream>>>(pred, tgt, Pb, Qb, Rb, tp);
    k_d<<<dim3(5, 10, NB * 4), dim3(32, 16), 0, stream>>>(Pb, Qb, Rb, partial, tp);
    k_reduce<<<1, 1024, 0, stream>>>(partial, out);
}

// Round 6
// 170.805 us; speedup vs baseline: 3.4995x; 1.1768x over previous
//
#include <hip/hip_runtime.h>
#include <math.h>

#define KS   15
#define RAD  7
#define L    160
#define VOL  (L*L*L)
#define NB   4
#define HTL  80             // output h-rows per k_wh block
#define HALO (HTL + 2*RAD)  // 94
#define WTL  32             // w-cols per k_wh block
#define DT   40             // k_d d-chunk per thread
#define NBLK (5*10*16)      // k_d grid blocks = 800

struct Taps {
    float g[KS];   // normalized 1D gaussian (symmetric)
    float h[KS];   // (x^2 - s^2)/s^4 * g (symmetric)
    float m;       // kernel mean (subtracted constant)
    float scale;   // 1 / (N * VOL)
};

// zero-padded float4 load from a row of length L
__device__ __forceinline__ float4 ld4z(const float* __restrict__ p, int w) {
    if (w >= 0 && w + 3 < L) return *reinterpret_cast<const float4*>(p + w);
    float4 r;
    r.x = (w     >= 0 && w     < L) ? p[w]     : 0.f;
    r.y = (w + 1 >= 0 && w + 1 < L) ? p[w + 1] : 0.f;
    r.z = (w + 2 >= 0 && w + 2 < L) ? p[w + 2] : 0.f;
    r.w = (w + 3 >= 0 && w + 3 < L) ? p[w + 3] : 0.f;
    return r;
}

// ============ Kernel 1: diff + W-conv + H-conv fused, tall-thin tile ========
// grid (10 = 5 w-tiles x 2 h-tiles, 160 d, 4 n), block 256.
// Writes P,Q,R in TRANSPOSED layout [n][h][d][w].
__global__ __launch_bounds__(256) void k_wh(const float* __restrict__ pred,
                                            const float* __restrict__ tgt,
                                            float* __restrict__ P,
                                            float* __restrict__ Q,
                                            float* __restrict__ R,
                                            Taps tp) {
    __shared__ float sA[HALO][WTL];
    __shared__ float sB[HALO][WTL];
    __shared__ float sC[HALO][WTL];

    const int tid = threadIdx.x;
    const int wt  = blockIdx.x >> 1;          // 0..4
    const int ht  = blockIdx.x & 1;           // 0..1
    const int wb  = wt * WTL;
    const int h0  = ht * HTL;
    const int d   = blockIdx.y;
    const int n   = blockIdx.z;
    const size_t nbase = (size_t)n * VOL;
    const float* __restrict__ pro = pred + nbase + (size_t)d * L * L;
    const float* __restrict__ tro = tgt  + nbase + (size_t)d * L * L;
    const bool wedge = (wt == 0) || (wt == 4);

    // ---- Stage A: diff + W-conv. 94 rows x 8 j-groups, 4 outputs/task ----
    for (int t = tid; t < HALO * 8; t += 256) {
        const int r = t >> 3;                 // 0..93
        const int j = t & 7;                  // 0..7
        const int h = h0 - RAD + r;
        float a[4], b[4], c[4];
        if (h >= 0 && h < L) {
            const float* pr = pro + h * L;
            const float* tr = tro + h * L;
            const int w0 = wb + 4 * j - 8;    // window base
            float dv[20];
            if (!wedge) {
#pragma unroll
                for (int q5 = 0; q5 < 5; ++q5) {
                    float4 pv = *reinterpret_cast<const float4*>(pr + w0 + 4 * q5);
                    float4 tv = *reinterpret_cast<const float4*>(tr + w0 + 4 * q5);
                    dv[4*q5+0] = pv.x - tv.x;
                    dv[4*q5+1] = pv.y - tv.y;
                    dv[4*q5+2] = pv.z - tv.z;
                    dv[4*q5+3] = pv.w - tv.w;
                }
            } else {
#pragma unroll
                for (int q5 = 0; q5 < 5; ++q5) {
                    float4 pv = ld4z(pr, w0 + 4 * q5);
                    float4 tv = ld4z(tr, w0 + 4 * q5);
                    dv[4*q5+0] = pv.x - tv.x;
                    dv[4*q5+1] = pv.y - tv.y;
                    dv[4*q5+2] = pv.z - tv.z;
                    dv[4*q5+3] = pv.w - tv.w;
                }
            }
#pragma unroll
            for (int k = 0; k < 4; ++k) {
                float mid = dv[k + 8];
                float aa = tp.g[7] * mid;
                float bb = tp.h[7] * mid;
                float cc = mid;
#pragma unroll
                for (int u = 0; u < 7; ++u) {     // symmetric taps
                    float s = dv[k + 1 + u] + dv[k + 15 - u];
                    aa += tp.g[u] * s;
                    bb += tp.h[u] * s;
                    cc += s;
                }
                a[k] = aa; b[k] = bb; c[k] = cc;
            }
        } else {
#pragma unroll
            for (int k = 0; k < 4; ++k) { a[k] = 0.f; b[k] = 0.f; c[k] = 0.f; }
        }
        *reinterpret_cast<float4*>(&sA[r][4*j]) = make_float4(a[0], a[1], a[2], a[3]);
        *reinterpret_cast<float4*>(&sB[r][4*j]) = make_float4(b[0], b[1], b[2], b[3]);
        *reinterpret_cast<float4*>(&sC[r][4*j]) = make_float4(c[0], c[1], c[2], c[3]);
    }
    __syncthreads();

    // ---- Stage B: H-conv; thread owns 10 consecutive h-rows at col tx ----
    {
        const int tx = tid & 31;
        const int ty = tid >> 5;              // 0..7
        float p[10], q[10], rb[10];
#pragma unroll
        for (int k = 0; k < 10; ++k) { p[k] = 0.f; q[k] = 0.f; rb[k] = 0.f; }
#pragma unroll
        for (int jr = 0; jr < 10 + 2 * RAD; ++jr) {   // 24 rows
            const float va = sA[10 * ty + jr][tx];
            const float vb = sB[10 * ty + jr][tx];
            const float vc = sC[10 * ty + jr][tx];
#pragma unroll
            for (int k = 0; k < 10; ++k) {
                const int t = jr - k;
                if (t >= 0 && t < KS) {               // compile-time resolved
                    p[k]  += tp.g[t] * va;
                    q[k]  += tp.h[t] * va + tp.g[t] * vb;
                    rb[k] += vc;
                }
            }
        }
#pragma unroll
        for (int k = 0; k < 10; ++k) {
            const int h = h0 + 10 * ty + k;
            const size_t o = nbase + ((size_t)h * L + d) * L + wb + tx;  // [n][h][d][w]
            P[o] = p[k]; Q[o] = q[k]; R[o] = rb[k];
        }
    }
}

// ============ Kernel 2: D-conv streaming + |.| + block reduce (unchanged) ====
__global__ __launch_bounds__(512) void k_d(const float* __restrict__ P,
                                           const float* __restrict__ Q,
                                           const float* __restrict__ R,
                                           float* __restrict__ partial,
                                           Taps tp) {
    const int tx = threadIdx.x;          // 0..31 (w)
    const int ty = threadIdx.y;          // 0..15 (h)
    const int w  = blockIdx.x * 32 + tx;
    const int h  = blockIdx.y * 16 + ty;
    const int gz = blockIdx.z;
    const int n  = gz >> 2;
    const int dc = gz & 3;
    const int d0 = dc * DT;

    const size_t base = (size_t)n * VOL + ((size_t)h * L) * L + w;
    const float* Pp = P + base;
    const float* Qp = Q + base;
    const float* Rp = R + base;

    float rp[KS], rq[KS], rc[KS];
    float box = 0.f;

#pragma unroll
    for (int i = 0; i < KS - 1; ++i) {
        int s = d0 - RAD + i;
        bool ok = (s >= 0);
        int off = s * L;
        float vp = ok ? Pp[off] : 0.f;
        float vq = ok ? Qp[off] : 0.f;
        float vc = ok ? Rp[off] : 0.f;
        rp[i] = vp; rq[i] = vq; rc[i] = vc;
        box += vc;
    }

    float acc = 0.f;
#pragma unroll
    for (int k = 0; k < DT; ++k) {
        int s = d0 + RAD + k;
        bool ok = (s < L);
        int off = s * L;
        float vp = ok ? Pp[off] : 0.f;
        float vq = ok ? Qp[off] : 0.f;
        float vc = ok ? Rp[off] : 0.f;
        const int ri = (KS - 1 + k) % KS;
        rp[ri] = vp; rq[ri] = vq; rc[ri] = vc;
        box += vc;

        float f = 0.f;
#pragma unroll
        for (int t = 0; t < KS; ++t) {
            const int ii = (k + t) % KS;
            f += tp.h[t] * rp[ii] + tp.g[t] * rq[ii];
        }
        f -= tp.m * box;
        acc += fabsf(f);

        box -= rc[k % KS];
    }
    acc *= tp.scale;

#pragma unroll
    for (int off = 32; off > 0; off >>= 1) acc += __shfl_down(acc, off);

    __shared__ float wsum[8];
    const int tid  = ty * 32 + tx;
    const int lane = tid & 63;
    const int wid  = tid >> 6;
    if (lane == 0) wsum[wid] = acc;
    __syncthreads();
    if (wid == 0) {
        float v = (lane < 8) ? wsum[lane] : 0.f;
#pragma unroll
        for (int off = 4; off > 0; off >>= 1) v += __shfl_down(v, off);
        if (lane == 0) {
            const int bid = (gz * gridDim.y + blockIdx.y) * gridDim.x + blockIdx.x;
            partial[bid] = v;
        }
    }
}

// ============ Final: sum 800 partials, single block, plain store ============
__global__ __launch_bounds__(1024) void k_reduce(const float* __restrict__ partial,
                                                 float* __restrict__ out) {
    float v = 0.f;
    for (int i = threadIdx.x; i < NBLK; i += 1024) v += partial[i];
#pragma unroll
    for (int off = 32; off > 0; off >>= 1) v += __shfl_down(v, off);

    __shared__ float wsum[16];
    const int lane = threadIdx.x & 63;
    const int wid  = threadIdx.x >> 6;
    if (lane == 0) wsum[wid] = v;
    __syncthreads();
    if (wid == 0) {
        float s = (lane < 16) ? wsum[lane] : 0.f;
#pragma unroll
        for (int off = 8; off > 0; off >>= 1) s += __shfl_down(s, off);
        if (lane == 0) out[0] = s;
    }
}

extern "C" void kernel_launch(void* const* d_in, const int* in_sizes, int n_in,
                              void* d_out, int out_size, void* d_ws, size_t ws_size,
                              hipStream_t stream) {
    const float* pred = (const float*)d_in[0];
    const float* tgt  = (const float*)d_in[1];
    float* out = (float*)d_out;
    float* ws  = (float*)d_ws;

    Taps tp;
    const double sigma = 1.5;
    double g1[KS], S = 0.0;
    for (int i = 0; i < KS; ++i) {
        double x = (double)(i - RAD);
        g1[i] = exp(-x * x / (2.0 * sigma * sigma));
        S += g1[i];
    }
    double sumH = 0.0;
    for (int i = 0; i < KS; ++i) {
        double x = (double)(i - RAD);
        double G = g1[i] / S;
        double H = (x * x - sigma * sigma) / (sigma * sigma * sigma * sigma) * G;
        tp.g[i] = (float)G;
        tp.h[i] = (float)H;
        sumH += H;
    }
    tp.m     = (float)(3.0 * sumH / (double)(KS * KS * KS));
    tp.scale = 1.0f / ((float)NB * (float)VOL);

    // ws: P[4*VOL] | Q[4*VOL] | R[4*VOL] | partial[800]
    float* Pb      = ws + (size_t)0 * NB * VOL;
    float* Qb      = ws + (size_t)1 * NB * VOL;
    float* Rb      = ws + (size_t)2 * NB * VOL;
    float* partial = ws + (size_t)3 * NB * VOL;

    k_wh<<<dim3(10, L, NB), dim3(256), 0, stream>>>(pred, tgt, Pb, Qb, Rb, tp);
    k_d<<<dim3(5, 10, NB * 4), dim3(32, 16), 0, stream>>>(Pb, Qb, Rb, partial, tp);
    k_reduce<<<1, 1024, 0, stream>>>(partial, out);
}